// Round 1
// baseline (713.928 us; speedup 1.0000x reference)
//
#include <hip/hip_runtime.h>
#include <hip/hip_bf16.h>

// Problem constants
#define BB 8
#define CC 192
#define C2 384
#define HH 128
#define WW 128
#define NN 16384          // H*W
#define NHEADS 4
#define HC 48             // head channels

// bf16 helpers on raw ushort storage
__device__ __forceinline__ float bfu2f(unsigned int u16) {
    return __uint_as_float(u16 << 16);
}
__device__ __forceinline__ unsigned short f2bfu(float f) {
    unsigned int u = __float_as_uint(f);
    unsigned int r = (u + 0x7fffu + ((u >> 16) & 1u)) >> 16;
    return (unsigned short)r;
}

// ---------------------------------------------------------------------------
// K1: qkv[b,o,n] = sum_c w_qkv[o,c] * x[b,c,n]   (fp32 in, bf16 out)
// 128x128 tile, 8x8 micro, K-chunk 8. grid (N/128, 384/128, B), 256 thr.
// ---------------------------------------------------------------------------
__global__ __launch_bounds__(256) void k1_qkv(
    const float* __restrict__ x, const float* __restrict__ w,
    unsigned short* __restrict__ qkv) {
  const int n0 = blockIdx.x * 128;
  const int o0 = blockIdx.y * 128;
  const int b  = blockIdx.z;
  __shared__ float As[8][128];
  __shared__ float Bs[8][128];
  const int t  = threadIdx.x;
  const int tx = t & 15;    // n micro (8 cols)
  const int ty = t >> 4;    // o micro (8 rows)
  const int aol = t & 127, akl = (t >> 7) * 4;
  const int bkl = t >> 5,  bnl = (t & 31) * 4;
  const float* xb = x + (size_t)b * CC * NN;
  float acc[8][8];
  #pragma unroll
  for (int i = 0; i < 8; ++i)
    #pragma unroll
    for (int j = 0; j < 8; ++j) acc[i][j] = 0.f;

  for (int k0 = 0; k0 < CC; k0 += 8) {
    const float4 av = *reinterpret_cast<const float4*>(&w[(o0 + aol) * CC + k0 + akl]);
    const float4 bv = *reinterpret_cast<const float4*>(&xb[(size_t)(k0 + bkl) * NN + n0 + bnl]);
    __syncthreads();
    As[akl + 0][aol] = av.x; As[akl + 1][aol] = av.y;
    As[akl + 2][aol] = av.z; As[akl + 3][aol] = av.w;
    *reinterpret_cast<float4*>(&Bs[bkl][bnl]) = bv;
    __syncthreads();
    #pragma unroll
    for (int kk = 0; kk < 8; ++kk) {
      float a[8], bb[8];
      *reinterpret_cast<float4*>(&a[0]) = *reinterpret_cast<const float4*>(&As[kk][ty * 8]);
      *reinterpret_cast<float4*>(&a[4]) = *reinterpret_cast<const float4*>(&As[kk][ty * 8 + 4]);
      *reinterpret_cast<float4*>(&bb[0]) = *reinterpret_cast<const float4*>(&Bs[kk][tx * 8]);
      *reinterpret_cast<float4*>(&bb[4]) = *reinterpret_cast<const float4*>(&Bs[kk][tx * 8 + 4]);
      #pragma unroll
      for (int i = 0; i < 8; ++i)
        #pragma unroll
        for (int j = 0; j < 8; ++j)
          acc[i][j] = fmaf(a[i], bb[j], acc[i][j]);
    }
  }
  #pragma unroll
  for (int i = 0; i < 8; ++i) {
    uint4 pk;
    pk.x = (unsigned int)f2bfu(acc[i][0]) | ((unsigned int)f2bfu(acc[i][1]) << 16);
    pk.y = (unsigned int)f2bfu(acc[i][2]) | ((unsigned int)f2bfu(acc[i][3]) << 16);
    pk.z = (unsigned int)f2bfu(acc[i][4]) | ((unsigned int)f2bfu(acc[i][5]) << 16);
    pk.w = (unsigned int)f2bfu(acc[i][6]) | ((unsigned int)f2bfu(acc[i][7]) << 16);
    *reinterpret_cast<uint4*>(&qkv[((size_t)b * C2 + o0 + ty * 8 + i) * NN + n0 + tx * 8]) = pk;
  }
}

// ---------------------------------------------------------------------------
// K2: 3x3 depthwise (SAME, cross-correlation) on bf16, per-channel weights.
// grid: (B*C2*64) blocks, 256 thr = 2 rows x 128 cols.
// ---------------------------------------------------------------------------
__global__ __launch_bounds__(256) void k2_dw(
    const unsigned short* __restrict__ qkv, const float* __restrict__ wdw,
    unsigned short* __restrict__ out) {
  const int gid   = blockIdx.x;
  const int ytile = gid & 63;
  const int bc    = gid >> 6;       // b*384 + ch
  const int ch    = bc % C2;
  const int t     = threadIdx.x;
  const int y     = ytile * 2 + (t >> 7);
  const int xc    = t & 127;
  const unsigned short* p = qkv + (size_t)bc * NN;
  const float* wv = wdw + ch * 9;
  float acc = 0.f;
  #pragma unroll
  for (int dy = 0; dy < 3; ++dy) {
    const int yy = y + dy - 1;
    if ((unsigned)yy < (unsigned)HH) {
      #pragma unroll
      for (int dx = 0; dx < 3; ++dx) {
        const int xx = xc + dx - 1;
        if ((unsigned)xx < (unsigned)WW)
          acc = fmaf(wv[dy * 3 + dx], bfu2f(p[yy * WW + xx]), acc);
      }
    }
  }
  out[(size_t)bc * NN + y * WW + xc] = f2bfu(acc);
}

// ---------------------------------------------------------------------------
// K3: partial Gram  Gpart[bh,chunk,c,d] = sum_{n in chunk} q[c,n]*q[d,n]
// grid (32, 16); block 256 (16x16, each thread a 3x3 pair tile).
// ---------------------------------------------------------------------------
__global__ __launch_bounds__(256) void k3_gram(
    const unsigned short* __restrict__ qkvd, float* __restrict__ gpart) {
  const int bh    = blockIdx.x;          // b*4 + h
  const int b     = bh >> 2, h = bh & 3;
  const int chunk = blockIdx.y;          // 0..15, 1024 pixels each
  const int t     = threadIdx.x;
  __shared__ unsigned short qs[48][136]; // +8 pad (keeps 16B align, spreads banks)
  const unsigned short* qb = qkvd + ((size_t)b * C2 + h * HC) * NN;
  const int c0 = (t >> 4) * 3, d0 = (t & 15) * 3;
  float acc[3][3];
  #pragma unroll
  for (int i = 0; i < 3; ++i)
    #pragma unroll
    for (int j = 0; j < 3; ++j) acc[i][j] = 0.f;

  for (int tile = 0; tile < 8; ++tile) {
    const int nb = chunk * 1024 + tile * 128;
    __syncthreads();
    for (int idx = t; idx < 768; idx += 256) {   // 48 rows * 16 groups of 8 bf16
      const int row = idx >> 4, cg = idx & 15;
      const uint4 v = *reinterpret_cast<const uint4*>(&qb[(size_t)row * NN + nb + cg * 8]);
      *reinterpret_cast<uint4*>(&qs[row][cg * 8]) = v;
    }
    __syncthreads();
    for (int nn = 0; nn < 128; nn += 2) {
      float cv[3][2], dv[3][2];
      #pragma unroll
      for (int i = 0; i < 3; ++i) {
        const unsigned int u = *reinterpret_cast<const unsigned int*>(&qs[c0 + i][nn]);
        cv[i][0] = bfu2f(u & 0xffffu); cv[i][1] = bfu2f(u >> 16);
      }
      #pragma unroll
      for (int j = 0; j < 3; ++j) {
        const unsigned int u = *reinterpret_cast<const unsigned int*>(&qs[d0 + j][nn]);
        dv[j][0] = bfu2f(u & 0xffffu); dv[j][1] = bfu2f(u >> 16);
      }
      #pragma unroll
      for (int i = 0; i < 3; ++i)
        #pragma unroll
        for (int j = 0; j < 3; ++j) {
          acc[i][j] = fmaf(cv[i][0], dv[j][0], acc[i][j]);
          acc[i][j] = fmaf(cv[i][1], dv[j][1], acc[i][j]);
        }
    }
  }
  float* gp = gpart + ((size_t)bh * 16 + chunk) * 2304;
  #pragma unroll
  for (int i = 0; i < 3; ++i)
    #pragma unroll
    for (int j = 0; j < 3; ++j)
      gp[(c0 + i) * 48 + d0 + j] = acc[i][j];
}

// ---------------------------------------------------------------------------
// K4: reduce partial Grams, normalize (folds q L2-norm), temperature, softmax.
// grid 32, block 256.
// ---------------------------------------------------------------------------
__global__ __launch_bounds__(256) void k4_soft(
    const float* __restrict__ gpart, const float* __restrict__ temp,
    float* __restrict__ attn) {
  const int bh = blockIdx.x;
  const int h  = bh & 3;
  const int t  = threadIdx.x;
  __shared__ float G[2304];
  __shared__ float rn[48];
  for (int idx = t; idx < 2304; idx += 256) {
    float s = 0.f;
    #pragma unroll
    for (int c = 0; c < 16; ++c) s += gpart[((size_t)bh * 16 + c) * 2304 + idx];
    G[idx] = s;
  }
  __syncthreads();
  if (t < 48) rn[t] = rsqrtf(G[t * 48 + t]);
  __syncthreads();
  if (t < 48) {
    const float tm = temp[h];
    float v[48];
    float mx = -1e30f;
    #pragma unroll
    for (int j = 0; j < 48; ++j) {
      v[j] = G[t * 48 + j] * rn[t] * rn[j] * tm;
      mx = fmaxf(mx, v[j]);
    }
    float s = 0.f;
    #pragma unroll
    for (int j = 0; j < 48; ++j) { v[j] = expf(v[j] - mx); s += v[j]; }
    const float inv = 1.f / s;
    #pragma unroll
    for (int j = 0; j < 48; ++j)
      attn[(size_t)bh * 2304 + t * 48 + j] = v[j] * inv;
  }
}

// ---------------------------------------------------------------------------
// K5: M[b,o,d] = sum_c w_proj[o, h(d)*48+c] * attn[b,h(d)][c, d%48]
// grid (192, 8), block 192.
// ---------------------------------------------------------------------------
__global__ __launch_bounds__(192) void k5_M(
    const float* __restrict__ wproj, const float* __restrict__ attn,
    float* __restrict__ Mb) {
  const int o = blockIdx.x;
  const int b = blockIdx.y;
  const int d = threadIdx.x;
  const int h = d / HC, dl = d % HC;
  const float* wrow = wproj + o * CC + h * HC;
  const float* at   = attn + ((size_t)(b * NHEADS + h)) * 2304;
  float s = 0.f;
  #pragma unroll
  for (int c = 0; c < HC; ++c) s = fmaf(wrow[c], at[c * HC + dl], s);
  Mb[((size_t)b * CC + o) * CC + d] = s;
}

// ---------------------------------------------------------------------------
// K6: out[b,o,n] = sum_d M[b,o,d] * v_dw[b,d,n]   (A fp32, B bf16, out fp32)
// Same SGEMM structure as K1; O=192 -> 2 o-tiles with masking.
// ---------------------------------------------------------------------------
__global__ __launch_bounds__(256) void k6_out(
    const float* __restrict__ Mb, const unsigned short* __restrict__ qkvd,
    float* __restrict__ out) {
  const int n0 = blockIdx.x * 128;
  const int o0 = blockIdx.y * 128;
  const int b  = blockIdx.z;
  __shared__ float As[8][128];
  __shared__ float Bs[8][128];
  const int t  = threadIdx.x;
  const int tx = t & 15;
  const int ty = t >> 4;
  const int aol = t & 127, akl = (t >> 7) * 4;
  const int bkl = t >> 5,  bnl = (t & 31) * 4;
  const float* A = Mb + (size_t)b * CC * CC;
  const unsigned short* vp = qkvd + ((size_t)b * C2 + CC) * NN;
  const bool aval = (o0 + aol) < CC;
  float acc[8][8];
  #pragma unroll
  for (int i = 0; i < 8; ++i)
    #pragma unroll
    for (int j = 0; j < 8; ++j) acc[i][j] = 0.f;

  for (int k0 = 0; k0 < CC; k0 += 8) {
    float4 av = make_float4(0.f, 0.f, 0.f, 0.f);
    if (aval) av = *reinterpret_cast<const float4*>(&A[(o0 + aol) * CC + k0 + akl]);
    const uint2 bvu = *reinterpret_cast<const uint2*>(&vp[(size_t)(k0 + bkl) * NN + n0 + bnl]);
    __syncthreads();
    As[akl + 0][aol] = av.x; As[akl + 1][aol] = av.y;
    As[akl + 2][aol] = av.z; As[akl + 3][aol] = av.w;
    float4 bf;
    bf.x = bfu2f(bvu.x & 0xffffu); bf.y = bfu2f(bvu.x >> 16);
    bf.z = bfu2f(bvu.y & 0xffffu); bf.w = bfu2f(bvu.y >> 16);
    *reinterpret_cast<float4*>(&Bs[bkl][bnl]) = bf;
    __syncthreads();
    #pragma unroll
    for (int kk = 0; kk < 8; ++kk) {
      float a[8], bb[8];
      *reinterpret_cast<float4*>(&a[0]) = *reinterpret_cast<const float4*>(&As[kk][ty * 8]);
      *reinterpret_cast<float4*>(&a[4]) = *reinterpret_cast<const float4*>(&As[kk][ty * 8 + 4]);
      *reinterpret_cast<float4*>(&bb[0]) = *reinterpret_cast<const float4*>(&Bs[kk][tx * 8]);
      *reinterpret_cast<float4*>(&bb[4]) = *reinterpret_cast<const float4*>(&Bs[kk][tx * 8 + 4]);
      #pragma unroll
      for (int i = 0; i < 8; ++i)
        #pragma unroll
        for (int j = 0; j < 8; ++j)
          acc[i][j] = fmaf(a[i], bb[j], acc[i][j]);
    }
  }
  #pragma unroll
  for (int i = 0; i < 8; ++i) {
    const int o = o0 + ty * 8 + i;
    if (o < CC) {
      float* op = &out[((size_t)b * CC + o) * NN + n0 + tx * 8];
      *reinterpret_cast<float4*>(op)     = *reinterpret_cast<float4*>(&acc[i][0]);
      *reinterpret_cast<float4*>(op + 4) = *reinterpret_cast<float4*>(&acc[i][4]);
    }
  }
}

// ---------------------------------------------------------------------------
extern "C" void kernel_launch(void* const* d_in, const int* in_sizes, int n_in,
                              void* d_out, int out_size, void* d_ws, size_t ws_size,
                              hipStream_t stream) {
  const float* x      = (const float*)d_in[0];
  const float* w_qkv  = (const float*)d_in[1];
  const float* w_dw   = (const float*)d_in[2];
  const float* w_proj = (const float*)d_in[3];
  const float* temp   = (const float*)d_in[4];
  float* out = (float*)d_out;

  // workspace layout (bytes)
  const size_t OFF_QKV   = 0;                   // bf16  8*384*16384 = 100,663,296 B
  const size_t OFF_QKVD  = 100663296ULL;        // bf16  same
  const size_t OFF_GPART = 201326592ULL;        // f32   32*16*2304  = 4,718,592 B
  const size_t OFF_ATTN  = 206045184ULL;        // f32   32*2304     = 294,912 B
  const size_t OFF_M     = 206340096ULL;        // f32   8*192*192   = 1,179,648 B
  const size_t NEEDED    = 207519744ULL;
  if (ws_size < NEEDED) return;  // signature: output stays zero

  char* ws = (char*)d_ws;
  unsigned short* qkv  = (unsigned short*)(ws + OFF_QKV);
  unsigned short* qkvd = (unsigned short*)(ws + OFF_QKVD);
  float* gpart = (float*)(ws + OFF_GPART);
  float* attn  = (float*)(ws + OFF_ATTN);
  float* Mb    = (float*)(ws + OFF_M);

  k1_qkv <<<dim3(NN / 128, C2 / 128, BB), 256, 0, stream>>>(x, w_qkv, qkv);
  k2_dw  <<<dim3(BB * C2 * 64), 256, 0, stream>>>(qkv, w_dw, qkvd);
  k3_gram<<<dim3(BB * NHEADS, 16), 256, 0, stream>>>(qkvd, gpart);
  k4_soft<<<dim3(BB * NHEADS), 256, 0, stream>>>(gpart, temp, attn);
  k5_M   <<<dim3(CC, BB), 192, 0, stream>>>(w_proj, attn, Mb);
  k6_out <<<dim3(NN / 128, 2, BB), 256, 0, stream>>>(Mb, qkvd, out);
}

// Round 2
// 291.103 us; speedup vs baseline: 2.4525x; 2.4525x over previous
//
#include <hip/hip_runtime.h>

#define BB 8
#define CC 192
#define C2 384
#define HH 128
#define WW 128
#define NN 16384
#define NHEADS 4
#define HC 48

typedef float f32x4 __attribute__((ext_vector_type(4)));
typedef short s16x4 __attribute__((ext_vector_type(4)));
typedef short s16x8 __attribute__((ext_vector_type(8)));
typedef unsigned short u16;
typedef u16 u16x4 __attribute__((ext_vector_type(4)));
typedef u16 u16x8 __attribute__((ext_vector_type(8)));

__device__ __forceinline__ float bfu2f(unsigned int u16v) {
  return __uint_as_float(u16v << 16);
}
__device__ __forceinline__ u16 f2bfu(float f) {
  unsigned int u = __float_as_uint(f);
  return (u16)((u + 0x7fffu + ((u >> 16) & 1u)) >> 16);
}

// ---------------------------------------------------------------------------
// K0a: w_qkv fp32 -> bf16 (384*192 = 73728 elems, 4/thread)
// ---------------------------------------------------------------------------
__global__ __launch_bounds__(256) void k0_wcvt(const float* __restrict__ w,
                                               u16* __restrict__ wbf) {
  const int i = (blockIdx.x * 256 + threadIdx.x) * 4;
  f32x4 v = *reinterpret_cast<const f32x4*>(&w[i]);
  u16x4 o;
  o[0] = f2bfu(v[0]); o[1] = f2bfu(v[1]); o[2] = f2bfu(v[2]); o[3] = f2bfu(v[3]);
  *reinterpret_cast<u16x4*>(&wbf[i]) = o;
}

// ---------------------------------------------------------------------------
// K0b: x fp32 -> bf16 (25165824 elems, 8/thread)
// ---------------------------------------------------------------------------
__global__ __launch_bounds__(256) void k0_xcvt(const float* __restrict__ x,
                                               u16* __restrict__ xbf) {
  const size_t i = ((size_t)blockIdx.x * 256 + threadIdx.x) * 8;
  f32x4 a = *reinterpret_cast<const f32x4*>(&x[i]);
  f32x4 b = *reinterpret_cast<const f32x4*>(&x[i + 4]);
  u16x8 o;
  o[0] = f2bfu(a[0]); o[1] = f2bfu(a[1]); o[2] = f2bfu(a[2]); o[3] = f2bfu(a[3]);
  o[4] = f2bfu(b[0]); o[5] = f2bfu(b[1]); o[6] = f2bfu(b[2]); o[7] = f2bfu(b[3]);
  *reinterpret_cast<u16x8*>(&xbf[i]) = o;
}

// ---------------------------------------------------------------------------
// K1: qkv[b,o,n] = sum_c wbf[o,c] * xbf[b,c,n]  via mfma_f32_16x16x32_bf16.
// Tile 128o x 128n, 4 waves (2x2, each 64x64 = 4x4 frags), BK=32, K=192.
// A frags: global b64 pairs (k = 4g+j and 16+4g+j). B: LDS [n][36] transposed.
// grid (128, 3, 8), 256 thr.
// ---------------------------------------------------------------------------
__global__ __launch_bounds__(256) void k1_qkv(
    const u16* __restrict__ xbf, const u16* __restrict__ wbf,
    u16* __restrict__ qkv) {
  const int n0 = blockIdx.x * 128;
  const int o0 = blockIdx.y * 128;
  const int b  = blockIdx.z;
  __shared__ u16 Bs[2][128 * 36];
  const int t = threadIdx.x;
  const int lane = t & 63, w = t >> 6;
  const int wo = w >> 1, wn = w & 1;
  const int l15 = lane & 15, g = lane >> 4;
  const int kp = t >> 4, sn0 = (t & 15) * 8;   // staging: k-pair, 8 n
  const u16* xb = xbf + (size_t)b * CC * NN + n0 + sn0;

  f32x4 acc[4][4];
  #pragma unroll
  for (int i = 0; i < 4; ++i)
    #pragma unroll
    for (int j = 0; j < 4; ++j)
      #pragma unroll
      for (int e = 0; e < 4; ++e) acc[i][j][e] = 0.f;

  u16x8 p0, p1;
  {
    const u16* r0 = xb + (size_t)(2 * kp) * NN;
    p0 = *reinterpret_cast<const u16x8*>(r0);
    p1 = *reinterpret_cast<const u16x8*>(r0 + NN);
  }
  {
    u16* bp = &Bs[0][0];
    #pragma unroll
    for (int j = 0; j < 8; ++j) {
      unsigned int pk = (unsigned int)p0[j] | ((unsigned int)p1[j] << 16);
      *reinterpret_cast<unsigned int*>(&bp[(sn0 + j) * 36 + 2 * kp]) = pk;
    }
  }

  for (int s = 0; s < 6; ++s) {
    __syncthreads();
    if (s < 5) {
      const u16* r0 = xb + (size_t)((s + 1) * 32 + 2 * kp) * NN;
      p0 = *reinterpret_cast<const u16x8*>(r0);
      p1 = *reinterpret_cast<const u16x8*>(r0 + NN);
    }
    const u16* bufc = &Bs[s & 1][0];
    s16x8 afr[4], bfr[4];
    #pragma unroll
    for (int mi = 0; mi < 4; ++mi) {
      const u16* ap = wbf + (size_t)(o0 + wo * 64 + mi * 16 + l15) * CC + s * 32 + 4 * g;
      s16x4 lo = *reinterpret_cast<const s16x4*>(ap);
      s16x4 hi = *reinterpret_cast<const s16x4*>(ap + 16);
      afr[mi] = __builtin_shufflevector(lo, hi, 0, 1, 2, 3, 4, 5, 6, 7);
    }
    #pragma unroll
    for (int nj = 0; nj < 4; ++nj) {
      const u16* bp2 = bufc + (wn * 64 + nj * 16 + l15) * 36 + 4 * g;
      s16x4 lo = *reinterpret_cast<const s16x4*>(bp2);
      s16x4 hi = *reinterpret_cast<const s16x4*>(bp2 + 16);
      bfr[nj] = __builtin_shufflevector(lo, hi, 0, 1, 2, 3, 4, 5, 6, 7);
    }
    #pragma unroll
    for (int mi = 0; mi < 4; ++mi)
      #pragma unroll
      for (int nj = 0; nj < 4; ++nj)
        acc[mi][nj] = __builtin_amdgcn_mfma_f32_16x16x32_bf16(afr[mi], bfr[nj], acc[mi][nj], 0, 0, 0);
    if (s < 5) {
      u16* bp = &Bs[(s + 1) & 1][0];
      #pragma unroll
      for (int j = 0; j < 8; ++j) {
        unsigned int pk = (unsigned int)p0[j] | ((unsigned int)p1[j] << 16);
        *reinterpret_cast<unsigned int*>(&bp[(sn0 + j) * 36 + 2 * kp]) = pk;
      }
    }
  }

  #pragma unroll
  for (int mi = 0; mi < 4; ++mi)
    #pragma unroll
    for (int nj = 0; nj < 4; ++nj) {
      const int orow = o0 + wo * 64 + mi * 16 + 4 * g;
      const int col  = n0 + wn * 64 + nj * 16 + l15;
      u16* qp = qkv + ((size_t)b * C2 + orow) * NN + col;
      #pragma unroll
      for (int r = 0; r < 4; ++r)
        qp[(size_t)r * NN] = f2bfu(acc[mi][nj][r]);
    }
}

// ---------------------------------------------------------------------------
// K2: 3x3 depthwise, vectorized 8 px/thread. grid (B*C2*8), 256 thr (16r x 16g).
// ---------------------------------------------------------------------------
__global__ __launch_bounds__(256) void k2_dw(
    const u16* __restrict__ qkv, const float* __restrict__ wdw,
    u16* __restrict__ out) {
  const int gid = blockIdx.x;
  const int rb = gid & 7;
  const int plane = gid >> 3;         // b*C2 + ch
  const int ch = plane % C2;
  const int t = threadIdx.x;
  const int row = rb * 16 + (t >> 4);
  const int x0 = (t & 15) * 8;
  const u16* p = qkv + (size_t)plane * NN;
  const float* wv = wdw + ch * 9;
  float o[8];
  #pragma unroll
  for (int j = 0; j < 8; ++j) o[j] = 0.f;
  #pragma unroll
  for (int dy = 0; dy < 3; ++dy) {
    const int yy = row + dy - 1;
    if ((unsigned)yy < (unsigned)HH) {
      const u16* rp = p + yy * WW;
      u16x8 m = *reinterpret_cast<const u16x8*>(&rp[x0]);
      float px[10];
      px[0] = (x0 > 0) ? bfu2f(rp[x0 - 1]) : 0.f;
      px[9] = (x0 < 120) ? bfu2f(rp[x0 + 8]) : 0.f;
      #pragma unroll
      for (int j = 0; j < 8; ++j) px[j + 1] = bfu2f(m[j]);
      const float w0 = wv[dy * 3 + 0], w1 = wv[dy * 3 + 1], w2 = wv[dy * 3 + 2];
      #pragma unroll
      for (int j = 0; j < 8; ++j)
        o[j] += w0 * px[j] + w1 * px[j + 1] + w2 * px[j + 2];
    }
  }
  u16x8 ov;
  #pragma unroll
  for (int j = 0; j < 8; ++j) ov[j] = f2bfu(o[j]);
  *reinterpret_cast<u16x8*>(&out[(size_t)plane * NN + row * WW + x0]) = ov;
}

// ---------------------------------------------------------------------------
// K3: partial Gram (unchanged)
// ---------------------------------------------------------------------------
__global__ __launch_bounds__(256) void k3_gram(
    const u16* __restrict__ qkvd, float* __restrict__ gpart) {
  const int bh = blockIdx.x;
  const int b = bh >> 2, h = bh & 3;
  const int chunk = blockIdx.y;
  const int t = threadIdx.x;
  __shared__ u16 qs[48][136];
  const u16* qb = qkvd + ((size_t)b * C2 + h * HC) * NN;
  const int c0 = (t >> 4) * 3, d0 = (t & 15) * 3;
  float acc[3][3];
  #pragma unroll
  for (int i = 0; i < 3; ++i)
    #pragma unroll
    for (int j = 0; j < 3; ++j) acc[i][j] = 0.f;

  for (int tile = 0; tile < 8; ++tile) {
    const int nb = chunk * 1024 + tile * 128;
    __syncthreads();
    for (int idx = t; idx < 768; idx += 256) {
      const int rowi = idx >> 4, cg = idx & 15;
      const uint4 v = *reinterpret_cast<const uint4*>(&qb[(size_t)rowi * NN + nb + cg * 8]);
      *reinterpret_cast<uint4*>(&qs[rowi][cg * 8]) = v;
    }
    __syncthreads();
    for (int nn = 0; nn < 128; nn += 2) {
      float cv[3][2], dv[3][2];
      #pragma unroll
      for (int i = 0; i < 3; ++i) {
        const unsigned int u = *reinterpret_cast<const unsigned int*>(&qs[c0 + i][nn]);
        cv[i][0] = bfu2f(u & 0xffffu); cv[i][1] = bfu2f(u >> 16);
      }
      #pragma unroll
      for (int j = 0; j < 3; ++j) {
        const unsigned int u = *reinterpret_cast<const unsigned int*>(&qs[d0 + j][nn]);
        dv[j][0] = bfu2f(u & 0xffffu); dv[j][1] = bfu2f(u >> 16);
      }
      #pragma unroll
      for (int i = 0; i < 3; ++i)
        #pragma unroll
        for (int j = 0; j < 3; ++j) {
          acc[i][j] = fmaf(cv[i][0], dv[j][0], acc[i][j]);
          acc[i][j] = fmaf(cv[i][1], dv[j][1], acc[i][j]);
        }
    }
  }
  float* gp = gpart + ((size_t)bh * 16 + chunk) * 2304;
  #pragma unroll
  for (int i = 0; i < 3; ++i)
    #pragma unroll
    for (int j = 0; j < 3; ++j)
      gp[(c0 + i) * 48 + d0 + j] = acc[i][j];
}

// ---------------------------------------------------------------------------
// K4: reduce + normalize + softmax (unchanged)
// ---------------------------------------------------------------------------
__global__ __launch_bounds__(256) void k4_soft(
    const float* __restrict__ gpart, const float* __restrict__ temp,
    float* __restrict__ attn) {
  const int bh = blockIdx.x;
  const int h = bh & 3;
  const int t = threadIdx.x;
  __shared__ float G[2304];
  __shared__ float rn[48];
  for (int idx = t; idx < 2304; idx += 256) {
    float s = 0.f;
    #pragma unroll
    for (int c = 0; c < 16; ++c) s += gpart[((size_t)bh * 16 + c) * 2304 + idx];
    G[idx] = s;
  }
  __syncthreads();
  if (t < 48) rn[t] = rsqrtf(G[t * 48 + t]);
  __syncthreads();
  if (t < 48) {
    const float tm = temp[h];
    float v[48];
    float mx = -1e30f;
    #pragma unroll
    for (int j = 0; j < 48; ++j) {
      v[j] = G[t * 48 + j] * rn[t] * rn[j] * tm;
      mx = fmaxf(mx, v[j]);
    }
    float s = 0.f;
    #pragma unroll
    for (int j = 0; j < 48; ++j) { v[j] = expf(v[j] - mx); s += v[j]; }
    const float inv = 1.f / s;
    #pragma unroll
    for (int j = 0; j < 48; ++j)
      attn[(size_t)bh * 2304 + t * 48 + j] = v[j] * inv;
  }
}

// ---------------------------------------------------------------------------
// K5: M[b,o,d] = sum_c w_proj[o, h(d)*48+c] * attn[b,h(d)][c, d%48]  -> bf16
// ---------------------------------------------------------------------------
__global__ __launch_bounds__(192) void k5_M(
    const float* __restrict__ wproj, const float* __restrict__ attn,
    u16* __restrict__ Mbf) {
  const int o = blockIdx.x;
  const int b = blockIdx.y;
  const int d = threadIdx.x;
  const int h = d / HC, dl = d % HC;
  const float* wrow = wproj + o * CC + h * HC;
  const float* at = attn + ((size_t)(b * NHEADS + h)) * 2304;
  float s = 0.f;
  #pragma unroll
  for (int c = 0; c < HC; ++c) s = fmaf(wrow[c], at[c * HC + dl], s);
  Mbf[((size_t)b * CC + o) * CC + d] = f2bfu(s);
}

// ---------------------------------------------------------------------------
// K6: out[b,o,n] = sum_d Mbf[b,o,d] * v[b,d,n]  via MFMA.
// Tile 64o x 128n, 4 waves (2x2, each 32x64 = 2x4 frags). grid (128, 3, 8).
// ---------------------------------------------------------------------------
__global__ __launch_bounds__(256) void k6_out(
    const u16* __restrict__ Mbf, const u16* __restrict__ qkvd,
    float* __restrict__ out) {
  const int n0 = blockIdx.x * 128;
  const int o0 = blockIdx.y * 64;
  const int b  = blockIdx.z;
  __shared__ u16 Bs[2][128 * 36];
  const int t = threadIdx.x;
  const int lane = t & 63, w = t >> 6;
  const int wo = w >> 1, wn = w & 1;
  const int l15 = lane & 15, g = lane >> 4;
  const int kp = t >> 4, sn0 = (t & 15) * 8;
  const u16* vb = qkvd + ((size_t)b * C2 + CC) * NN + n0 + sn0;
  const u16* Ab = Mbf + (size_t)b * CC * CC;

  f32x4 acc[2][4];
  #pragma unroll
  for (int i = 0; i < 2; ++i)
    #pragma unroll
    for (int j = 0; j < 4; ++j)
      #pragma unroll
      for (int e = 0; e < 4; ++e) acc[i][j][e] = 0.f;

  u16x8 p0, p1;
  {
    const u16* r0 = vb + (size_t)(2 * kp) * NN;
    p0 = *reinterpret_cast<const u16x8*>(r0);
    p1 = *reinterpret_cast<const u16x8*>(r0 + NN);
  }
  {
    u16* bp = &Bs[0][0];
    #pragma unroll
    for (int j = 0; j < 8; ++j) {
      unsigned int pk = (unsigned int)p0[j] | ((unsigned int)p1[j] << 16);
      *reinterpret_cast<unsigned int*>(&bp[(sn0 + j) * 36 + 2 * kp]) = pk;
    }
  }

  for (int s = 0; s < 6; ++s) {
    __syncthreads();
    if (s < 5) {
      const u16* r0 = vb + (size_t)((s + 1) * 32 + 2 * kp) * NN;
      p0 = *reinterpret_cast<const u16x8*>(r0);
      p1 = *reinterpret_cast<const u16x8*>(r0 + NN);
    }
    const u16* bufc = &Bs[s & 1][0];
    s16x8 afr[2], bfr[4];
    #pragma unroll
    for (int mi = 0; mi < 2; ++mi) {
      const u16* ap = Ab + (size_t)(o0 + wo * 32 + mi * 16 + l15) * CC + s * 32 + 4 * g;
      s16x4 lo = *reinterpret_cast<const s16x4*>(ap);
      s16x4 hi = *reinterpret_cast<const s16x4*>(ap + 16);
      afr[mi] = __builtin_shufflevector(lo, hi, 0, 1, 2, 3, 4, 5, 6, 7);
    }
    #pragma unroll
    for (int nj = 0; nj < 4; ++nj) {
      const u16* bp2 = bufc + (wn * 64 + nj * 16 + l15) * 36 + 4 * g;
      s16x4 lo = *reinterpret_cast<const s16x4*>(bp2);
      s16x4 hi = *reinterpret_cast<const s16x4*>(bp2 + 16);
      bfr[nj] = __builtin_shufflevector(lo, hi, 0, 1, 2, 3, 4, 5, 6, 7);
    }
    #pragma unroll
    for (int mi = 0; mi < 2; ++mi)
      #pragma unroll
      for (int nj = 0; nj < 4; ++nj)
        acc[mi][nj] = __builtin_amdgcn_mfma_f32_16x16x32_bf16(afr[mi], bfr[nj], acc[mi][nj], 0, 0, 0);
    if (s < 5) {
      u16* bp = &Bs[(s + 1) & 1][0];
      #pragma unroll
      for (int j = 0; j < 8; ++j) {
        unsigned int pk = (unsigned int)p0[j] | ((unsigned int)p1[j] << 16);
        *reinterpret_cast<unsigned int*>(&bp[(sn0 + j) * 36 + 2 * kp]) = pk;
      }
    }
  }

  #pragma unroll
  for (int mi = 0; mi < 2; ++mi)
    #pragma unroll
    for (int nj = 0; nj < 4; ++nj) {
      const int orow = o0 + wo * 32 + mi * 16 + 4 * g;
      const int col  = n0 + wn * 64 + nj * 16 + l15;
      float* op = out + ((size_t)b * CC + orow) * NN + col;
      #pragma unroll
      for (int r = 0; r < 4; ++r)
        op[(size_t)r * NN] = acc[mi][nj][r];
    }
}

// ---------------------------------------------------------------------------
extern "C" void kernel_launch(void* const* d_in, const int* in_sizes, int n_in,
                              void* d_out, int out_size, void* d_ws, size_t ws_size,
                              hipStream_t stream) {
  const float* x      = (const float*)d_in[0];
  const float* w_qkv  = (const float*)d_in[1];
  const float* w_dw   = (const float*)d_in[2];
  const float* w_proj = (const float*)d_in[3];
  const float* temp   = (const float*)d_in[4];
  float* out = (float*)d_out;

  // workspace layout (bytes)
  const size_t OFF_QKV   = 0;               // bf16  8*384*16384      = 100,663,296
  const size_t OFF_QKVD  = 100663296ULL;    // bf16  same; first 50 MB doubles as xbf
  const size_t OFF_GPART = 201326592ULL;    // f32   32*16*2304       = 4,718,592
  const size_t OFF_ATTN  = 206045184ULL;    // f32   32*2304          = 294,912
  const size_t OFF_M     = 206340096ULL;    // bf16  8*192*192        = 589,824
  const size_t OFF_WBF   = 206929920ULL;    // bf16  384*192          = 147,456
  const size_t NEEDED    = 207077376ULL;
  if (ws_size < NEEDED) return;

  char* ws = (char*)d_ws;
  u16* qkv   = (u16*)(ws + OFF_QKV);
  u16* qkvd  = (u16*)(ws + OFF_QKVD);
  u16* xbf   = (u16*)(ws + OFF_QKVD);   // aliases qkvd; dead before k2 writes
  float* gpart = (float*)(ws + OFF_GPART);
  float* attn  = (float*)(ws + OFF_ATTN);
  u16* Mbf   = (u16*)(ws + OFF_M);
  u16* wbf   = (u16*)(ws + OFF_WBF);

  k0_wcvt<<<dim3(72), 256, 0, stream>>>(w_qkv, wbf);
  k0_xcvt<<<dim3(12288), 256, 0, stream>>>(x, xbf);
  k1_qkv <<<dim3(128, 3, 8), 256, 0, stream>>>(xbf, wbf, qkv);
  k2_dw  <<<dim3(BB * C2 * 8), 256, 0, stream>>>(qkv, w_dw, qkvd);
  k3_gram<<<dim3(BB * NHEADS, 16), 256, 0, stream>>>(qkvd, gpart);
  k4_soft<<<dim3(BB * NHEADS), 256, 0, stream>>>(gpart, temp, attn);
  k5_M   <<<dim3(CC, BB), 192, 0, stream>>>(w_proj, attn, Mbf);
  k6_out <<<dim3(128, 3, 8), 256, 0, stream>>>(Mbf, qkvd, out);
}

// Round 3
// 272.554 us; speedup vs baseline: 2.6194x; 1.0681x over previous
//
#include <hip/hip_runtime.h>

#define BB 8
#define CC 192
#define C2 384
#define HH 128
#define WW 128
#define NN 16384
#define NHEADS 4
#define HC 48

typedef float f32x4 __attribute__((ext_vector_type(4)));
typedef short s16x4 __attribute__((ext_vector_type(4)));
typedef short s16x8 __attribute__((ext_vector_type(8)));
typedef unsigned short u16;
typedef u16 u16x4 __attribute__((ext_vector_type(4)));
typedef u16 u16x8 __attribute__((ext_vector_type(8)));

__device__ __forceinline__ float bfu2f(unsigned int u16v) {
  return __uint_as_float(u16v << 16);
}
__device__ __forceinline__ u16 f2bfu(float f) {
  unsigned int u = __float_as_uint(f);
  return (u16)((u + 0x7fffu + ((u >> 16) & 1u)) >> 16);
}
__device__ __forceinline__ s16x8 ldpair(const u16* p) {
  s16x4 lo = *reinterpret_cast<const s16x4*>(p);
  s16x4 hi = *reinterpret_cast<const s16x4*>(p + 16);
  return __builtin_shufflevector(lo, hi, 0, 1, 2, 3, 4, 5, 6, 7);
}

// ---------------------------------------------------------------------------
// K0a: w_qkv fp32 -> bf16
// ---------------------------------------------------------------------------
__global__ __launch_bounds__(256) void k0_wcvt(const float* __restrict__ w,
                                               u16* __restrict__ wbf) {
  const int i = (blockIdx.x * 256 + threadIdx.x) * 4;
  f32x4 v = *reinterpret_cast<const f32x4*>(&w[i]);
  u16x4 o;
  o[0] = f2bfu(v[0]); o[1] = f2bfu(v[1]); o[2] = f2bfu(v[2]); o[3] = f2bfu(v[3]);
  *reinterpret_cast<u16x4*>(&wbf[i]) = o;
}

// ---------------------------------------------------------------------------
// K1: qkv[b,o,n] = sum_c wbf[o,c] * x[b,c,n] (f32 x converted inline).
// 8 waves, tile 128o x 128n, BK=32, K=192. A reg-double-buffered from global;
// B staged in LDS [n][36] with XOR-swizzled 8B k-blocks (h ^= n&7).
// grid (128, 3, 8), 512 thr.
// ---------------------------------------------------------------------------
__global__ __launch_bounds__(512, 4) void k1_qkv(
    const float* __restrict__ x, const u16* __restrict__ wbf,
    u16* __restrict__ qkv) {
  const int n0 = blockIdx.x * 128;
  const int o0 = blockIdx.y * 128;
  const int b  = blockIdx.z;
  __shared__ u16 Bs[2][128 * 36];
  const int t = threadIdx.x, lane = t & 63, w = t >> 6;
  const int wo = w >> 1, wn = w & 1;
  const int l15 = lane & 15, g = lane >> 4;
  const int kp = t & 15, ng = t >> 4;          // staging: k-pair, n-group(4)
  const int hh = kp >> 1, lo2 = (kp & 1) << 1;
  const float* xb = x + (size_t)b * CC * NN + n0 + ng * 4;

  f32x4 acc[2][4];
  #pragma unroll
  for (int i = 0; i < 2; ++i)
    #pragma unroll
    for (int j = 0; j < 4; ++j)
      #pragma unroll
      for (int e = 0; e < 4; ++e) acc[i][j][e] = 0.f;

  const u16* arow0 = wbf + (size_t)(o0 + wo * 32 + l15) * CC + 4 * g;
  const u16* arow1 = arow0 + 16 * CC;
  s16x8 aC0 = ldpair(arow0), aC1 = ldpair(arow1);

  // stage s = 0
  {
    f32x4 r0 = *reinterpret_cast<const f32x4*>(xb + (size_t)(2 * kp) * NN);
    f32x4 r1 = *reinterpret_cast<const f32x4*>(xb + (size_t)(2 * kp + 1) * NN);
    u16* buf = &Bs[0][0];
    #pragma unroll
    for (int i = 0; i < 4; ++i) {
      const int n = ng * 4 + i;
      unsigned int pk = (unsigned int)f2bfu(r0[i]) | ((unsigned int)f2bfu(r1[i]) << 16);
      *reinterpret_cast<unsigned int*>(buf + n * 36 + 4 * (hh ^ (n & 7)) + lo2) = pk;
    }
  }
  __syncthreads();

  s16x8 aN0, aN1;
  f32x4 p0, p1;
  #pragma unroll
  for (int s = 0; s < 6; ++s) {
    if (s < 5) {
      aN0 = ldpair(arow0 + (s + 1) * 32);
      aN1 = ldpair(arow1 + (s + 1) * 32);
      p0 = *reinterpret_cast<const f32x4*>(xb + (size_t)((s + 1) * 32 + 2 * kp) * NN);
      p1 = *reinterpret_cast<const f32x4*>(xb + (size_t)((s + 1) * 32 + 2 * kp + 1) * NN);
    }
    const u16* bufc = &Bs[s & 1][0];
    s16x8 bfr[4];
    #pragma unroll
    for (int nj = 0; nj < 4; ++nj) {
      const int n = wn * 64 + nj * 16 + l15;
      const int gs = g ^ (n & 7);
      const u16* bp = bufc + n * 36;
      s16x4 lo = *reinterpret_cast<const s16x4*>(bp + 4 * gs);
      s16x4 hi = *reinterpret_cast<const s16x4*>(bp + 4 * (gs ^ 4));
      bfr[nj] = __builtin_shufflevector(lo, hi, 0, 1, 2, 3, 4, 5, 6, 7);
    }
    #pragma unroll
    for (int nj = 0; nj < 4; ++nj) {
      acc[0][nj] = __builtin_amdgcn_mfma_f32_16x16x32_bf16(aC0, bfr[nj], acc[0][nj], 0, 0, 0);
      acc[1][nj] = __builtin_amdgcn_mfma_f32_16x16x32_bf16(aC1, bfr[nj], acc[1][nj], 0, 0, 0);
    }
    if (s < 5) {
      u16* buf = &Bs[(s + 1) & 1][0];
      #pragma unroll
      for (int i = 0; i < 4; ++i) {
        const int n = ng * 4 + i;
        unsigned int pk = (unsigned int)f2bfu(p0[i]) | ((unsigned int)f2bfu(p1[i]) << 16);
        *reinterpret_cast<unsigned int*>(buf + n * 36 + 4 * (hh ^ (n & 7)) + lo2) = pk;
      }
      aC0 = aN0; aC1 = aN1;
    }
    __syncthreads();
  }

  #pragma unroll
  for (int mi = 0; mi < 2; ++mi)
    #pragma unroll
    for (int nj = 0; nj < 4; ++nj) {
      const int orow = o0 + wo * 32 + mi * 16 + 4 * g;
      const int col  = n0 + wn * 64 + nj * 16 + l15;
      u16* qp = qkv + ((size_t)b * C2 + orow) * NN + col;
      #pragma unroll
      for (int r = 0; r < 4; ++r)
        qp[(size_t)r * NN] = f2bfu(acc[mi][nj][r]);
    }
}

// ---------------------------------------------------------------------------
// K2: 3x3 depthwise, 8 px/thread (unchanged).
// ---------------------------------------------------------------------------
__global__ __launch_bounds__(256) void k2_dw(
    const u16* __restrict__ qkv, const float* __restrict__ wdw,
    u16* __restrict__ out) {
  const int gid = blockIdx.x;
  const int rb = gid & 7;
  const int plane = gid >> 3;
  const int ch = plane % C2;
  const int t = threadIdx.x;
  const int row = rb * 16 + (t >> 4);
  const int x0 = (t & 15) * 8;
  const u16* p = qkv + (size_t)plane * NN;
  const float* wv = wdw + ch * 9;
  float o[8];
  #pragma unroll
  for (int j = 0; j < 8; ++j) o[j] = 0.f;
  #pragma unroll
  for (int dy = 0; dy < 3; ++dy) {
    const int yy = row + dy - 1;
    if ((unsigned)yy < (unsigned)HH) {
      const u16* rp = p + yy * WW;
      u16x8 m = *reinterpret_cast<const u16x8*>(&rp[x0]);
      float px[10];
      px[0] = (x0 > 0) ? bfu2f(rp[x0 - 1]) : 0.f;
      px[9] = (x0 < 120) ? bfu2f(rp[x0 + 8]) : 0.f;
      #pragma unroll
      for (int j = 0; j < 8; ++j) px[j + 1] = bfu2f(m[j]);
      const float w0 = wv[dy * 3 + 0], w1 = wv[dy * 3 + 1], w2 = wv[dy * 3 + 2];
      #pragma unroll
      for (int j = 0; j < 8; ++j)
        o[j] += w0 * px[j] + w1 * px[j + 1] + w2 * px[j + 2];
    }
  }
  u16x8 ov;
  #pragma unroll
  for (int j = 0; j < 8; ++j) ov[j] = f2bfu(o[j]);
  *reinterpret_cast<u16x8*>(&out[(size_t)plane * NN + row * WW + x0]) = ov;
}

// ---------------------------------------------------------------------------
// K3: partial Gram via MFMA. Symmetric: one frag set serves A and B.
// grid (32 bh, 16 chunks of 1024 n), 256 thr = 4 waves x 256 n each.
// ---------------------------------------------------------------------------
__global__ __launch_bounds__(256) void k3_gram(
    const u16* __restrict__ qkvd, float* __restrict__ gpart) {
  const int bh = blockIdx.x, b = bh >> 2, h = bh & 3;
  const int chunk = blockIdx.y;
  const int t = threadIdx.x, lane = t & 63, wv = t >> 6;
  const int l15 = lane & 15, g = lane >> 4;
  __shared__ float red[4][2304];
  const u16* qb = qkvd + ((size_t)b * C2 + h * HC) * NN;

  f32x4 acc[3][3];
  #pragma unroll
  for (int i = 0; i < 3; ++i)
    #pragma unroll
    for (int j = 0; j < 3; ++j)
      #pragma unroll
      for (int e = 0; e < 4; ++e) acc[i][j][e] = 0.f;

  const int nbase = chunk * 1024 + wv * 256;
  #pragma unroll 2
  for (int st = 0; st < 8; ++st) {
    const int n = nbase + st * 32;
    s16x8 cf[3];
    #pragma unroll
    for (int i = 0; i < 3; ++i)
      cf[i] = ldpair(qb + (size_t)(i * 16 + l15) * NN + n + 4 * g);
    #pragma unroll
    for (int i = 0; i < 3; ++i)
      #pragma unroll
      for (int j = 0; j < 3; ++j)
        acc[i][j] = __builtin_amdgcn_mfma_f32_16x16x32_bf16(cf[i], cf[j], acc[i][j], 0, 0, 0);
  }
  #pragma unroll
  for (int i = 0; i < 3; ++i)
    #pragma unroll
    for (int j = 0; j < 3; ++j)
      #pragma unroll
      for (int r = 0; r < 4; ++r)
        red[wv][(i * 16 + 4 * g + r) * 48 + j * 16 + l15] = acc[i][j][r];
  __syncthreads();
  float* gp = gpart + ((size_t)bh * 16 + chunk) * 2304;
  for (int idx = t; idx < 2304; idx += 256)
    gp[idx] = red[0][idx] + red[1][idx] + red[2][idx] + red[3][idx];
}

// ---------------------------------------------------------------------------
// K4: reduce + normalize + softmax (unchanged, 16 chunks)
// ---------------------------------------------------------------------------
__global__ __launch_bounds__(256) void k4_soft(
    const float* __restrict__ gpart, const float* __restrict__ temp,
    float* __restrict__ attn) {
  const int bh = blockIdx.x;
  const int h = bh & 3;
  const int t = threadIdx.x;
  __shared__ float G[2304];
  __shared__ float rn[48];
  for (int idx = t; idx < 2304; idx += 256) {
    float s = 0.f;
    #pragma unroll
    for (int c = 0; c < 16; ++c) s += gpart[((size_t)bh * 16 + c) * 2304 + idx];
    G[idx] = s;
  }
  __syncthreads();
  if (t < 48) rn[t] = rsqrtf(G[t * 48 + t]);
  __syncthreads();
  if (t < 48) {
    const float tm = temp[h];
    float v[48];
    float mx = -1e30f;
    #pragma unroll
    for (int j = 0; j < 48; ++j) {
      v[j] = G[t * 48 + j] * rn[t] * rn[j] * tm;
      mx = fmaxf(mx, v[j]);
    }
    float s = 0.f;
    #pragma unroll
    for (int j = 0; j < 48; ++j) { v[j] = expf(v[j] - mx); s += v[j]; }
    const float inv = 1.f / s;
    #pragma unroll
    for (int j = 0; j < 48; ++j)
      attn[(size_t)bh * 2304 + t * 48 + j] = v[j] * inv;
  }
}

// ---------------------------------------------------------------------------
// K5: M = w_proj x blockdiag(attn) -> bf16 (unchanged)
// ---------------------------------------------------------------------------
__global__ __launch_bounds__(192) void k5_M(
    const float* __restrict__ wproj, const float* __restrict__ attn,
    u16* __restrict__ Mbf) {
  const int o = blockIdx.x;
  const int b = blockIdx.y;
  const int d = threadIdx.x;
  const int h = d / HC, dl = d % HC;
  const float* wrow = wproj + o * CC + h * HC;
  const float* at = attn + ((size_t)(b * NHEADS + h)) * 2304;
  float s = 0.f;
  #pragma unroll
  for (int c = 0; c < HC; ++c) s = fmaf(wrow[c], at[c * HC + dl], s);
  Mbf[((size_t)b * CC + o) * CC + d] = f2bfu(s);
}

// ---------------------------------------------------------------------------
// K6: out[b,o,n] = sum_d Mbf[b,o,d] * v[b,d,n]. 8 waves, tile 64o x 256n.
// Same swizzled-LDS structure as K1. grid (64, 3, 8), 512 thr.
// ---------------------------------------------------------------------------
__global__ __launch_bounds__(512, 4) void k6_out(
    const u16* __restrict__ Mbf, const u16* __restrict__ qkvd,
    float* __restrict__ out) {
  const int n0 = blockIdx.x * 256;
  const int o0 = blockIdx.y * 64;
  const int b  = blockIdx.z;
  __shared__ u16 Bs[2][256 * 36];
  const int t = threadIdx.x, lane = t & 63, w = t >> 6;
  const int wo = w >> 2, wn = w & 3;
  const int l15 = lane & 15, g = lane >> 4;
  const int kp = t & 15, ng = t >> 4;          // staging: k-pair, n-group(8)
  const int hh = kp >> 1, lo2 = (kp & 1) << 1;
  const u16* vb = qkvd + ((size_t)b * C2 + CC) * NN + n0 + ng * 8;
  const u16* Ab = Mbf + (size_t)b * CC * CC;

  f32x4 acc[2][4];
  #pragma unroll
  for (int i = 0; i < 2; ++i)
    #pragma unroll
    for (int j = 0; j < 4; ++j)
      #pragma unroll
      for (int e = 0; e < 4; ++e) acc[i][j][e] = 0.f;

  const u16* arow0 = Ab + (size_t)(o0 + wo * 32 + l15) * CC + 4 * g;
  const u16* arow1 = arow0 + 16 * CC;
  s16x8 aC0 = ldpair(arow0), aC1 = ldpair(arow1);

  {
    u16x8 r0 = *reinterpret_cast<const u16x8*>(vb + (size_t)(2 * kp) * NN);
    u16x8 r1 = *reinterpret_cast<const u16x8*>(vb + (size_t)(2 * kp + 1) * NN);
    u16* buf = &Bs[0][0];
    #pragma unroll
    for (int i = 0; i < 8; ++i) {
      const int n = ng * 8 + i;
      unsigned int pk = (unsigned int)r0[i] | ((unsigned int)r1[i] << 16);
      *reinterpret_cast<unsigned int*>(buf + n * 36 + 4 * (hh ^ (n & 7)) + lo2) = pk;
    }
  }
  __syncthreads();

  s16x8 aN0, aN1;
  u16x8 p0, p1;
  #pragma unroll
  for (int s = 0; s < 6; ++s) {
    if (s < 5) {
      aN0 = ldpair(arow0 + (s + 1) * 32);
      aN1 = ldpair(arow1 + (s + 1) * 32);
      p0 = *reinterpret_cast<const u16x8*>(vb + (size_t)((s + 1) * 32 + 2 * kp) * NN);
      p1 = *reinterpret_cast<const u16x8*>(vb + (size_t)((s + 1) * 32 + 2 * kp + 1) * NN);
    }
    const u16* bufc = &Bs[s & 1][0];
    s16x8 bfr[4];
    #pragma unroll
    for (int nj = 0; nj < 4; ++nj) {
      const int n = wn * 64 + nj * 16 + l15;
      const int gs = g ^ (n & 7);
      const u16* bp = bufc + n * 36;
      s16x4 lo = *reinterpret_cast<const s16x4*>(bp + 4 * gs);
      s16x4 hi = *reinterpret_cast<const s16x4*>(bp + 4 * (gs ^ 4));
      bfr[nj] = __builtin_shufflevector(lo, hi, 0, 1, 2, 3, 4, 5, 6, 7);
    }
    #pragma unroll
    for (int nj = 0; nj < 4; ++nj) {
      acc[0][nj] = __builtin_amdgcn_mfma_f32_16x16x32_bf16(aC0, bfr[nj], acc[0][nj], 0, 0, 0);
      acc[1][nj] = __builtin_amdgcn_mfma_f32_16x16x32_bf16(aC1, bfr[nj], acc[1][nj], 0, 0, 0);
    }
    if (s < 5) {
      u16* buf = &Bs[(s + 1) & 1][0];
      #pragma unroll
      for (int i = 0; i < 8; ++i) {
        const int n = ng * 8 + i;
        unsigned int pk = (unsigned int)p0[i] | ((unsigned int)p1[i] << 16);
        *reinterpret_cast<unsigned int*>(buf + n * 36 + 4 * (hh ^ (n & 7)) + lo2) = pk;
      }
      aC0 = aN0; aC1 = aN1;
    }
    __syncthreads();
  }

  #pragma unroll
  for (int mi = 0; mi < 2; ++mi)
    #pragma unroll
    for (int nj = 0; nj < 4; ++nj) {
      const int orow = o0 + wo * 32 + mi * 16 + 4 * g;
      const int col  = n0 + wn * 64 + nj * 16 + l15;
      float* op = out + ((size_t)b * CC + orow) * NN + col;
      #pragma unroll
      for (int r = 0; r < 4; ++r)
        op[(size_t)r * NN] = acc[mi][nj][r];
    }
}

// ---------------------------------------------------------------------------
extern "C" void kernel_launch(void* const* d_in, const int* in_sizes, int n_in,
                              void* d_out, int out_size, void* d_ws, size_t ws_size,
                              hipStream_t stream) {
  const float* x      = (const float*)d_in[0];
  const float* w_qkv  = (const float*)d_in[1];
  const float* w_dw   = (const float*)d_in[2];
  const float* w_proj = (const float*)d_in[3];
  const float* temp   = (const float*)d_in[4];
  float* out = (float*)d_out;

  const size_t OFF_QKV   = 0;               // bf16  8*384*16384 = 100,663,296
  const size_t OFF_QKVD  = 100663296ULL;    // bf16  same
  const size_t OFF_GPART = 201326592ULL;    // f32   32*16*2304  = 4,718,592
  const size_t OFF_ATTN  = 206045184ULL;    // f32   32*2304     = 294,912
  const size_t OFF_M     = 206340096ULL;    // bf16  8*192*192   = 589,824
  const size_t OFF_WBF   = 206929920ULL;    // bf16  384*192     = 147,456
  const size_t NEEDED    = 207077376ULL;
  if (ws_size < NEEDED) return;

  char* ws = (char*)d_ws;
  u16* qkv   = (u16*)(ws + OFF_QKV);
  u16* qkvd  = (u16*)(ws + OFF_QKVD);
  float* gpart = (float*)(ws + OFF_GPART);
  float* attn  = (float*)(ws + OFF_ATTN);
  u16* Mbf   = (u16*)(ws + OFF_M);
  u16* wbf   = (u16*)(ws + OFF_WBF);

  k0_wcvt<<<dim3(72), 256, 0, stream>>>(w_qkv, wbf);
  k1_qkv <<<dim3(128, 3, 8), 512, 0, stream>>>(x, wbf, qkv);
  k2_dw  <<<dim3(BB * C2 * 8), 256, 0, stream>>>(qkv, w_dw, qkvd);
  k3_gram<<<dim3(BB * NHEADS, 16), 256, 0, stream>>>(qkvd, gpart);
  k4_soft<<<dim3(BB * NHEADS), 256, 0, stream>>>(gpart, temp, attn);
  k5_M   <<<dim3(CC, BB), 192, 0, stream>>>(w_proj, attn, Mbf);
  k6_out <<<dim3(64, 3, 8), 512, 0, stream>>>(Mbf, qkvd, out);
}

// Round 4
// 224.199 us; speedup vs baseline: 3.1844x; 1.2157x over previous
//
#include <hip/hip_runtime.h>

#define BB 8
#define CC 192
#define C2 384
#define HH 128
#define WW 128
#define NN 16384
#define NHEADS 4
#define HC 48
#define LT 40   // LDS row stride in u16 (80 B): 16B-aligned, conflict-free b128 reads

typedef float f32x4 __attribute__((ext_vector_type(4)));
typedef float f32x16 __attribute__((ext_vector_type(16)));
typedef short s16x4 __attribute__((ext_vector_type(4)));
typedef short s16x8 __attribute__((ext_vector_type(8)));
typedef unsigned short u16;
typedef u16 u16x2 __attribute__((ext_vector_type(2)));
typedef u16 u16x4 __attribute__((ext_vector_type(4)));
typedef u16 u16x8 __attribute__((ext_vector_type(8)));
typedef unsigned int u32;

__device__ __forceinline__ float bfu2f(u32 u16v) {
  return __uint_as_float(u16v << 16);
}
__device__ __forceinline__ u16 f2bfu(float f) {
  u32 u = __float_as_uint(f);
  return (u16)((u + 0x7fffu + ((u >> 16) & 1u)) >> 16);
}
__device__ __forceinline__ s16x8 ldpair(const u16* p) {
  s16x4 lo = *reinterpret_cast<const s16x4*>(p);
  s16x4 hi = *reinterpret_cast<const s16x4*>(p + 16);
  return __builtin_shufflevector(lo, hi, 0, 1, 2, 3, 4, 5, 6, 7);
}

// ---------------------------------------------------------------------------
// K0a: w_qkv fp32 -> bf16
// ---------------------------------------------------------------------------
__global__ __launch_bounds__(256) void k0_wcvt(const float* __restrict__ w,
                                               u16* __restrict__ wbf) {
  const int i = (blockIdx.x * 256 + threadIdx.x) * 4;
  f32x4 v = *reinterpret_cast<const f32x4*>(&w[i]);
  u16x4 o;
  o[0] = f2bfu(v[0]); o[1] = f2bfu(v[1]); o[2] = f2bfu(v[2]); o[3] = f2bfu(v[3]);
  *reinterpret_cast<u16x4*>(&wbf[i]) = o;
}

// ---------------------------------------------------------------------------
// K1: qkv[b,o,n] = sum_c wbf[o,c] * x[b,c,n] via mfma_f32_32x32x16_bf16.
// 4 waves (2x2), tile 128o x 128n, wave-tile 64x64 = 2x2 frags of 32x32.
// A and B staged in LDS [row][LT], k-contiguous; frags = single b128 reads.
// grid (128, 3, 8), 256 thr.
// ---------------------------------------------------------------------------
__global__ __launch_bounds__(256) void k1_qkv(
    const float* __restrict__ x, const u16* __restrict__ wbf,
    u16* __restrict__ qkv) {
  const int n0 = blockIdx.x * 128;
  const int o0 = blockIdx.y * 128;
  const int b  = blockIdx.z;
  __shared__ u16 As[2][128 * LT];
  __shared__ u16 Bs[2][128 * LT];
  const int t = threadIdx.x, lane = t & 63, w = t >> 6;
  const int wo = w >> 1, wn = w & 1;
  const int l31 = lane & 31, g2 = lane >> 5;
  const int sng = t & 15, skp = t >> 4;   // B staging: n = sng+16i, c-pair skp
  const int arow = t >> 1, ac2 = t & 1;   // A staging: row, 16-col half

  const float* xb = x + (size_t)b * CC * NN + n0 + sng;
  const u16* wrow = wbf + (size_t)(o0 + arow) * CC + ac2 * 16;

  f32x16 acc[2][2];
  #pragma unroll
  for (int i = 0; i < 2; ++i)
    #pragma unroll
    for (int j = 0; j < 2; ++j)
      #pragma unroll
      for (int e = 0; e < 16; ++e) acc[i][j][e] = 0.f;

  uint4 ar0, ar1;
  u32 br[8];

  // ---- LOAD(s=0)
  {
    ar0 = *reinterpret_cast<const uint4*>(&wrow[0]);
    ar1 = *reinterpret_cast<const uint4*>(&wrow[8]);
    const float* xs = xb + (size_t)(2 * skp) * NN;
    #pragma unroll
    for (int i = 0; i < 8; ++i) {
      float f0 = xs[16 * i];
      float f1 = xs[NN + 16 * i];
      br[i] = (u32)f2bfu(f0) | ((u32)f2bfu(f1) << 16);
    }
  }
  // ---- WRITE(buf 0)
  {
    *reinterpret_cast<uint4*>(&As[0][arow * LT + ac2 * 16]) = ar0;
    *reinterpret_cast<uint4*>(&As[0][arow * LT + ac2 * 16 + 8]) = ar1;
    #pragma unroll
    for (int i = 0; i < 8; ++i)
      *reinterpret_cast<u32*>(&Bs[0][(sng + 16 * i) * LT + 2 * skp]) = br[i];
  }
  __syncthreads();

  for (int s = 0; s < 6; ++s) {
    if (s < 5) {
      ar0 = *reinterpret_cast<const uint4*>(&wrow[(s + 1) * 32]);
      ar1 = *reinterpret_cast<const uint4*>(&wrow[(s + 1) * 32 + 8]);
      const float* xs = xb + (size_t)((s + 1) * 32 + 2 * skp) * NN;
      #pragma unroll
      for (int i = 0; i < 8; ++i) {
        float f0 = xs[16 * i];
        float f1 = xs[NN + 16 * i];
        br[i] = (u32)f2bfu(f0) | ((u32)f2bfu(f1) << 16);
      }
    }
    const u16* as_ = &As[s & 1][0];
    const u16* bs_ = &Bs[s & 1][0];
    s16x8 af[2][2], bfv[2][2];
    #pragma unroll
    for (int mi = 0; mi < 2; ++mi)
      #pragma unroll
      for (int h = 0; h < 2; ++h)
        af[mi][h] = *reinterpret_cast<const s16x8*>(
            &as_[(wo * 64 + mi * 32 + l31) * LT + h * 16 + g2 * 8]);
    #pragma unroll
    for (int nj = 0; nj < 2; ++nj)
      #pragma unroll
      for (int h = 0; h < 2; ++h)
        bfv[nj][h] = *reinterpret_cast<const s16x8*>(
            &bs_[(wn * 64 + nj * 32 + l31) * LT + h * 16 + g2 * 8]);
    #pragma unroll
    for (int mi = 0; mi < 2; ++mi)
      #pragma unroll
      for (int nj = 0; nj < 2; ++nj)
        #pragma unroll
        for (int h = 0; h < 2; ++h)
          acc[mi][nj] = __builtin_amdgcn_mfma_f32_32x32x16_bf16(
              af[mi][h], bfv[nj][h], acc[mi][nj], 0, 0, 0);
    if (s < 5) {
      const int nb = (s + 1) & 1;
      *reinterpret_cast<uint4*>(&As[nb][arow * LT + ac2 * 16]) = ar0;
      *reinterpret_cast<uint4*>(&As[nb][arow * LT + ac2 * 16 + 8]) = ar1;
      #pragma unroll
      for (int i = 0; i < 8; ++i)
        *reinterpret_cast<u32*>(&Bs[nb][(sng + 16 * i) * LT + 2 * skp]) = br[i];
    }
    __syncthreads();
  }

  #pragma unroll
  for (int mi = 0; mi < 2; ++mi)
    #pragma unroll
    for (int nj = 0; nj < 2; ++nj) {
      const int ob = o0 + wo * 64 + mi * 32;
      const int n  = n0 + wn * 64 + nj * 32 + l31;
      #pragma unroll
      for (int r = 0; r < 16; ++r) {
        const int row = (r & 3) + 8 * (r >> 2) + 4 * g2;
        qkv[((size_t)b * C2 + ob + row) * NN + n] = f2bfu(acc[mi][nj][r]);
      }
    }
}

// ---------------------------------------------------------------------------
// K2: 3x3 depthwise, 8 px/thread (unchanged).
// ---------------------------------------------------------------------------
__global__ __launch_bounds__(256) void k2_dw(
    const u16* __restrict__ qkv, const float* __restrict__ wdw,
    u16* __restrict__ out) {
  const int gid = blockIdx.x;
  const int rb = gid & 7;
  const int plane = gid >> 3;
  const int ch = plane % C2;
  const int t = threadIdx.x;
  const int row = rb * 16 + (t >> 4);
  const int x0 = (t & 15) * 8;
  const u16* p = qkv + (size_t)plane * NN;
  const float* wv = wdw + ch * 9;
  float o[8];
  #pragma unroll
  for (int j = 0; j < 8; ++j) o[j] = 0.f;
  #pragma unroll
  for (int dy = 0; dy < 3; ++dy) {
    const int yy = row + dy - 1;
    if ((unsigned)yy < (unsigned)HH) {
      const u16* rp = p + yy * WW;
      u16x8 m = *reinterpret_cast<const u16x8*>(&rp[x0]);
      float px[10];
      px[0] = (x0 > 0) ? bfu2f(rp[x0 - 1]) : 0.f;
      px[9] = (x0 < 120) ? bfu2f(rp[x0 + 8]) : 0.f;
      #pragma unroll
      for (int j = 0; j < 8; ++j) px[j + 1] = bfu2f(m[j]);
      const float w0 = wv[dy * 3 + 0], w1 = wv[dy * 3 + 1], w2 = wv[dy * 3 + 2];
      #pragma unroll
      for (int j = 0; j < 8; ++j)
        o[j] += w0 * px[j] + w1 * px[j + 1] + w2 * px[j + 2];
    }
  }
  u16x8 ov;
  #pragma unroll
  for (int j = 0; j < 8; ++j) ov[j] = f2bfu(o[j]);
  *reinterpret_cast<u16x8*>(&out[(size_t)plane * NN + row * WW + x0]) = ov;
}

// ---------------------------------------------------------------------------
// K3: partial Gram via MFMA (symmetric; same frag both operands).
// ---------------------------------------------------------------------------
__global__ __launch_bounds__(256) void k3_gram(
    const u16* __restrict__ qkvd, float* __restrict__ gpart) {
  const int bh = blockIdx.x, b = bh >> 2, h = bh & 3;
  const int chunk = blockIdx.y;
  const int t = threadIdx.x, lane = t & 63, wv = t >> 6;
  const int l15 = lane & 15, g = lane >> 4;
  __shared__ float red[4][2304];
  const u16* qb = qkvd + ((size_t)b * C2 + h * HC) * NN;

  f32x4 acc[3][3];
  #pragma unroll
  for (int i = 0; i < 3; ++i)
    #pragma unroll
    for (int j = 0; j < 3; ++j)
      #pragma unroll
      for (int e = 0; e < 4; ++e) acc[i][j][e] = 0.f;

  const int nbase = chunk * 1024 + wv * 256;
  #pragma unroll 2
  for (int st = 0; st < 8; ++st) {
    const int n = nbase + st * 32;
    s16x8 cf[3];
    #pragma unroll
    for (int i = 0; i < 3; ++i)
      cf[i] = ldpair(qb + (size_t)(i * 16 + l15) * NN + n + 4 * g);
    #pragma unroll
    for (int i = 0; i < 3; ++i)
      #pragma unroll
      for (int j = 0; j < 3; ++j)
        acc[i][j] = __builtin_amdgcn_mfma_f32_16x16x32_bf16(cf[i], cf[j], acc[i][j], 0, 0, 0);
  }
  #pragma unroll
  for (int i = 0; i < 3; ++i)
    #pragma unroll
    for (int j = 0; j < 3; ++j)
      #pragma unroll
      for (int r = 0; r < 4; ++r)
        red[wv][(i * 16 + 4 * g + r) * 48 + j * 16 + l15] = acc[i][j][r];
  __syncthreads();
  float* gp = gpart + ((size_t)bh * 16 + chunk) * 2304;
  for (int idx = t; idx < 2304; idx += 256)
    gp[idx] = red[0][idx] + red[1][idx] + red[2][idx] + red[3][idx];
}

// ---------------------------------------------------------------------------
// K4: reduce + normalize + softmax (unchanged)
// ---------------------------------------------------------------------------
__global__ __launch_bounds__(256) void k4_soft(
    const float* __restrict__ gpart, const float* __restrict__ temp,
    float* __restrict__ attn) {
  const int bh = blockIdx.x;
  const int h = bh & 3;
  const int t = threadIdx.x;
  __shared__ float G[2304];
  __shared__ float rn[48];
  for (int idx = t; idx < 2304; idx += 256) {
    float s = 0.f;
    #pragma unroll
    for (int c = 0; c < 16; ++c) s += gpart[((size_t)bh * 16 + c) * 2304 + idx];
    G[idx] = s;
  }
  __syncthreads();
  if (t < 48) rn[t] = rsqrtf(G[t * 48 + t]);
  __syncthreads();
  if (t < 48) {
    const float tm = temp[h];
    float v[48];
    float mx = -1e30f;
    #pragma unroll
    for (int j = 0; j < 48; ++j) {
      v[j] = G[t * 48 + j] * rn[t] * rn[j] * tm;
      mx = fmaxf(mx, v[j]);
    }
    float s = 0.f;
    #pragma unroll
    for (int j = 0; j < 48; ++j) { v[j] = expf(v[j] - mx); s += v[j]; }
    const float inv = 1.f / s;
    #pragma unroll
    for (int j = 0; j < 48; ++j)
      attn[(size_t)bh * 2304 + t * 48 + j] = v[j] * inv;
  }
}

// ---------------------------------------------------------------------------
// K5: M = w_proj x blockdiag(attn) -> bf16 (unchanged)
// ---------------------------------------------------------------------------
__global__ __launch_bounds__(192) void k5_M(
    const float* __restrict__ wproj, const float* __restrict__ attn,
    u16* __restrict__ Mbf) {
  const int o = blockIdx.x;
  const int b = blockIdx.y;
  const int d = threadIdx.x;
  const int h = d / HC, dl = d % HC;
  const float* wrow = wproj + o * CC + h * HC;
  const float* at = attn + ((size_t)(b * NHEADS + h)) * 2304;
  float s = 0.f;
  #pragma unroll
  for (int c = 0; c < HC; ++c) s = fmaf(wrow[c], at[c * HC + dl], s);
  Mbf[((size_t)b * CC + o) * CC + d] = f2bfu(s);
}

// ---------------------------------------------------------------------------
// K6: out[b,o,n] = sum_d Mbf[b,o,d] * v[b,d,n] via mfma_f32_32x32x16_bf16.
// 4 waves (2x2), tile 64o x 256n, wave-tile 32o x 128n = 1x4 frags.
// grid (64, 3, 8), 256 thr.
// ---------------------------------------------------------------------------
__global__ __launch_bounds__(256) void k6_out(
    const u16* __restrict__ Mbf, const u16* __restrict__ qkvd,
    float* __restrict__ out) {
  const int n0 = blockIdx.x * 256;
  const int o0 = blockIdx.y * 64;
  const int b  = blockIdx.z;
  __shared__ u16 As[2][64 * LT];
  __shared__ u16 Bs[2][256 * LT];
  const int t = threadIdx.x, lane = t & 63, w = t >> 6;
  const int wo = w >> 1, wn = w & 1;
  const int l31 = lane & 31, g2 = lane >> 5;
  const int sng = t & 15, skp = t >> 4;   // B staging: n-pairs
  const int arow = t >> 2, ap = t & 3;    // A staging: 64 rows x 4 chunks

  const u16* vb = qkvd + ((size_t)b * C2 + CC) * NN + n0;
  const u16* mrow = Mbf + ((size_t)b * CC + o0 + arow) * CC + ap * 8;

  f32x16 acc[4];
  #pragma unroll
  for (int j = 0; j < 4; ++j)
    #pragma unroll
    for (int e = 0; e < 16; ++e) acc[j][e] = 0.f;

  uint4 ar0;
  u32 br[16];

  // LOAD(0)
  {
    ar0 = *reinterpret_cast<const uint4*>(&mrow[0]);
    const u16* vs = vb + (size_t)(2 * skp) * NN + 2 * sng;
    #pragma unroll
    for (int i = 0; i < 8; ++i) {
      u16x2 a0 = *reinterpret_cast<const u16x2*>(vs + 32 * i);
      u16x2 a1 = *reinterpret_cast<const u16x2*>(vs + NN + 32 * i);
      br[2 * i]     = (u32)a0[0] | ((u32)a1[0] << 16);
      br[2 * i + 1] = (u32)a0[1] | ((u32)a1[1] << 16);
    }
  }
  {
    *reinterpret_cast<uint4*>(&As[0][arow * LT + ap * 8]) = ar0;
    #pragma unroll
    for (int i = 0; i < 8; ++i) {
      const int n = 2 * sng + 32 * i;
      *reinterpret_cast<u32*>(&Bs[0][n * LT + 2 * skp]) = br[2 * i];
      *reinterpret_cast<u32*>(&Bs[0][(n + 1) * LT + 2 * skp]) = br[2 * i + 1];
    }
  }
  __syncthreads();

  for (int s = 0; s < 6; ++s) {
    if (s < 5) {
      ar0 = *reinterpret_cast<const uint4*>(&mrow[(s + 1) * 32]);
      const u16* vs = vb + (size_t)((s + 1) * 32 + 2 * skp) * NN + 2 * sng;
      #pragma unroll
      for (int i = 0; i < 8; ++i) {
        u16x2 a0 = *reinterpret_cast<const u16x2*>(vs + 32 * i);
        u16x2 a1 = *reinterpret_cast<const u16x2*>(vs + NN + 32 * i);
        br[2 * i]     = (u32)a0[0] | ((u32)a1[0] << 16);
        br[2 * i + 1] = (u32)a0[1] | ((u32)a1[1] << 16);
      }
    }
    const u16* as_ = &As[s & 1][0];
    const u16* bs_ = &Bs[s & 1][0];
    s16x8 af[2], bfv[4][2];
    #pragma unroll
    for (int h = 0; h < 2; ++h)
      af[h] = *reinterpret_cast<const s16x8*>(
          &as_[(wo * 32 + l31) * LT + h * 16 + g2 * 8]);
    #pragma unroll
    for (int nj = 0; nj < 4; ++nj)
      #pragma unroll
      for (int h = 0; h < 2; ++h)
        bfv[nj][h] = *reinterpret_cast<const s16x8*>(
            &bs_[(wn * 128 + nj * 32 + l31) * LT + h * 16 + g2 * 8]);
    #pragma unroll
    for (int nj = 0; nj < 4; ++nj)
      #pragma unroll
      for (int h = 0; h < 2; ++h)
        acc[nj] = __builtin_amdgcn_mfma_f32_32x32x16_bf16(
            af[h], bfv[nj][h], acc[nj], 0, 0, 0);
    if (s < 5) {
      const int nb = (s + 1) & 1;
      *reinterpret_cast<uint4*>(&As[nb][arow * LT + ap * 8]) = ar0;
      #pragma unroll
      for (int i = 0; i < 8; ++i) {
        const int n = 2 * sng + 32 * i;
        *reinterpret_cast<u32*>(&Bs[nb][n * LT + 2 * skp]) = br[2 * i];
        *reinterpret_cast<u32*>(&Bs[nb][(n + 1) * LT + 2 * skp]) = br[2 * i + 1];
      }
    }
    __syncthreads();
  }

  #pragma unroll
  for (int nj = 0; nj < 4; ++nj) {
    const int ob = o0 + wo * 32;
    const int n  = n0 + wn * 128 + nj * 32 + l31;
    #pragma unroll
    for (int r = 0; r < 16; ++r) {
      const int row = (r & 3) + 8 * (r >> 2) + 4 * g2;
      out[((size_t)b * CC + ob + row) * NN + n] = acc[nj][r];
    }
  }
}

// ---------------------------------------------------------------------------
extern "C" void kernel_launch(void* const* d_in, const int* in_sizes, int n_in,
                              void* d_out, int out_size, void* d_ws, size_t ws_size,
                              hipStream_t stream) {
  const float* x      = (const float*)d_in[0];
  const float* w_qkv  = (const float*)d_in[1];
  const float* w_dw   = (const float*)d_in[2];
  const float* w_proj = (const float*)d_in[3];
  const float* temp   = (const float*)d_in[4];
  float* out = (float*)d_out;

  const size_t OFF_QKV   = 0;               // bf16  8*384*16384 = 100,663,296
  const size_t OFF_QKVD  = 100663296ULL;    // bf16  same
  const size_t OFF_GPART = 201326592ULL;    // f32   32*16*2304  = 4,718,592
  const size_t OFF_ATTN  = 206045184ULL;    // f32   32*2304     = 294,912
  const size_t OFF_M     = 206340096ULL;    // bf16  8*192*192   = 589,824
  const size_t OFF_WBF   = 206929920ULL;    // bf16  384*192     = 147,456
  const size_t NEEDED    = 207077376ULL;
  if (ws_size < NEEDED) return;

  char* ws = (char*)d_ws;
  u16* qkv   = (u16*)(ws + OFF_QKV);
  u16* qkvd  = (u16*)(ws + OFF_QKVD);
  float* gpart = (float*)(ws + OFF_GPART);
  float* attn  = (float*)(ws + OFF_ATTN);
  u16* Mbf   = (u16*)(ws + OFF_M);
  u16* wbf   = (u16*)(ws + OFF_WBF);

  k0_wcvt<<<dim3(72), 256, 0, stream>>>(w_qkv, wbf);
  k1_qkv <<<dim3(128, 3, 8), 256, 0, stream>>>(x, wbf, qkv);
  k2_dw  <<<dim3(BB * C2 * 8), 256, 0, stream>>>(qkv, w_dw, qkvd);
  k3_gram<<<dim3(BB * NHEADS, 16), 256, 0, stream>>>(qkvd, gpart);
  k4_soft<<<dim3(BB * NHEADS), 256, 0, stream>>>(gpart, temp, attn);
  k5_M   <<<dim3(CC, BB), 192, 0, stream>>>(w_proj, attn, Mbf);
  k6_out <<<dim3(64, 3, 8), 256, 0, stream>>>(Mbf, qkvd, out);
}